// Round 1
// baseline (7261.886 us; speedup 1.0000x reference)
//
#include <hip/hip_runtime.h>

#define N_ROWS 131072
#define DIM 64
#define K_CODES 4096
#define BROWS 256            // rows per block = 4 waves x 64
#define CK 64                // cols per chunk
#define NCH (K_CODES / CK)   // 64 chunks
#define EPS 0.015625f        // flag margin in score space (>=15x bf16x3 error bound)
#define HEPS 0.0078125f      // EPS/2 in d-space (score = -2*d)
#define RB 8                 // refine rows per pass

typedef __attribute__((ext_vector_type(8))) short short8;
typedef __attribute__((ext_vector_type(4))) float f32x4;

__device__ inline unsigned short bf16rn(float f) {      // round-nearest-even
    unsigned int u = __float_as_uint(f);
    u += 0x7FFFu + ((u >> 16) & 1u);
    return (unsigned short)(u >> 16);
}
// order-preserving float -> uint32 (finite scores)
__device__ inline unsigned int fkey(float f) {
    unsigned int u = __float_as_uint(f);
    return (u & 0x80000000u) ? ~u : (u | 0x80000000u);
}

__device__ __forceinline__ void gll16(const void* g, void* l) {
    __builtin_amdgcn_global_load_lds(
        (const __attribute__((address_space(1))) void*)g,
        (__attribute__((address_space(3))) void*)l, 16, 0, 0);
}

// ---- e2[k] = sum_d embed[k][d]^2 (exact fp32) ----
__global__ void e2_kernel(const float* __restrict__ embed, float* __restrict__ e2) {
    int k = blockIdx.x * blockDim.x + threadIdx.x;
    const float4* e = reinterpret_cast<const float4*>(embed + (size_t)k * DIM);
    float s = 0.f;
#pragma unroll
    for (int i = 0; i < DIM / 4; ++i) {
        float4 v = e[i];
        s = fmaf(v.x, v.x, s);
        s = fmaf(v.y, v.y, s);
        s = fmaf(v.z, v.z, s);
        s = fmaf(v.w, v.w, s);
    }
    e2[k] = s;
}

// ---- pack embed -> bf16 hi/lo "LDS images", one 16KB image per chunk ----
// Image layout per chunk: bytes [0,8192) = hi half, [8192,16384) = lo half.
// Within each half, phys byte p holds logical byte L = p ^ (((p>>7)&7)<<4)
// of a row-major [64 codes][64 bf16] tile (XOR swizzle keeps ds_read_b128
// bank-even; 16B granules map to 16B granules so linear global_load_lds works).
__global__ void pack_kernel(const float* __restrict__ embed,
                            unsigned short* __restrict__ ebf) {
    const int g = blockIdx.x * blockDim.x + threadIdx.x;   // granule id (16B each)
    const int ch  = g >> 10;                               // 1024 granules / chunk
    const int off = (g & 1023) << 4;                       // byte in 16KB image
    const int lohalf = off >> 13;                          // 0 = hi, 1 = lo
    const int p = off & 8191;
    const int L = p ^ (((p >> 7) & 7) << 4);
    const int row = L >> 7;
    const int d0  = (L & 127) >> 1;
    const float* ep = embed + ((size_t)(ch * 64 + row) * DIM + d0);
    float4 f0 = *(const float4*)ep;
    float4 f1 = *(const float4*)(ep + 4);
    float w[8] = {f0.x, f0.y, f0.z, f0.w, f1.x, f1.y, f1.z, f1.w};
    unsigned short o[8];
#pragma unroll
    for (int j = 0; j < 8; ++j) {
        unsigned short hb = bf16rn(w[j]);
        if (lohalf == 0) {
            o[j] = hb;
        } else {
            float hf = __uint_as_float(((unsigned int)hb) << 16);
            o[j] = bf16rn(w[j] - hf);
        }
    }
    *(uint4*)(ebf + (size_t)g * 8) = *(uint4*)o;
}

// ---- MFMA distance + fused top-2 argmax(dot - e2/2) ----
// Wave = 64 rows; A (xh,xl frags) in registers for the whole sweep.
// B tiles DMA'd via global_load_lds (double-buffered, prefetch-early/drain-late).
// acc init = -e2/2, then acc += xh*eh + xh*el + xl*eh (bf16x3); score = -2*acc.
__global__ __launch_bounds__(256, 2) void dist_argmin_kernel(
        const float* __restrict__ x, const unsigned short* __restrict__ ebf,
        const float* __restrict__ e2g, int* __restrict__ ind_ws,
        float* __restrict__ ind_out, int* __restrict__ cnt,
        int* __restrict__ list) {
    __shared__ unsigned short ebuf[2][8192];   // 2 x 16KB chunk images
    __shared__ float e2l[K_CODES];             // 16KB

    const int tid  = threadIdx.x;
    const int l15  = tid & 15;
    const int quad = (tid >> 4) & 3;
    const int wave = tid >> 6;
    const int r0w  = blockIdx.x * BROWS + wave * 64;

    const int lane16 = (tid & 63) << 4;
    const int uoff   = wave << 10;
    const char* ebfB = (const char*)ebf;
    char* lds0 = (char*)&ebuf[0][0];

#define STAGE(CH, BUF) do {                                              \
        const char* _g = ebfB + ((size_t)(CH) << 14) + uoff + lane16;    \
        char* _l = lds0 + ((BUF) << 14) + uoff;                          \
        gll16(_g,         _l);                                           \
        gll16(_g + 4096,  _l + 4096);                                    \
        gll16(_g + 8192,  _l + 8192);                                    \
        gll16(_g + 12288, _l + 12288);                                   \
    } while (0)

    // issue chunk-0 DMA first so it flies under the prologue work
    STAGE(0, 0);

    // e2 -> LDS (one-time)
    {
        const float4* s = (const float4*)e2g;
        float4* d = (float4*)e2l;
        for (int i = tid; i < K_CODES / 4; i += 256) d[i] = s[i];
    }

    // A-frags: A[m=l15][k=quad*8+j] per 16x16x32; rows 16i+l15, k-windows 32s+8q
    short8 ah[4][2], al[4][2];
#pragma unroll
    for (int i = 0; i < 4; ++i)
#pragma unroll
        for (int s = 0; s < 2; ++s) {
            const float* xp = x + (size_t)(r0w + 16 * i + l15) * DIM + 32 * s + 8 * quad;
            float4 f0 = *(const float4*)xp;
            float4 f1 = *(const float4*)(xp + 4);
            float w[8] = {f0.x, f0.y, f0.z, f0.w, f1.x, f1.y, f1.z, f1.w};
            short8 h, l;
#pragma unroll
            for (int j = 0; j < 8; ++j) {
                unsigned short hb = bf16rn(w[j]);
                float hf = __uint_as_float(((unsigned int)hb) << 16);
                h[j] = (short)hb;
                l[j] = (short)bf16rn(w[j] - hf);
            }
            ah[i][s] = h;
            al[i][s] = l;
        }

    // per-lane swizzled LDS frag bases (shorts): row=16j+l15, k-slot = quad, half h
    // phys = j*2048B + l15*128B + (((h<<2)|quad) ^ (l15&7))<<4
    const int fld = quad ^ (l15 & 7);
    const unsigned short* eb = &ebuf[0][0];
    const unsigned short* va0 = eb + ((l15 * 128 + (fld << 4)) >> 1);
    const unsigned short* va1 = eb + ((l15 * 128 + ((fld ^ 4) << 4)) >> 1);

    float s1[16], s2[16];
    int c1[16];
#pragma unroll
    for (int t = 0; t < 16; ++t) { s1[t] = -3.4e38f; s2[t] = -3.4e38f; c1[t] = 0; }

    __syncthreads();   // chunk 0 landed (drains vmcnt), e2l ready

    int cur = 0;
    for (int ch = 0; ch < NCH; ++ch) {
        STAGE((ch + 1) & (NCH - 1), cur ^ 1);   // prefetch next (wraps harmlessly)

        const int c0 = ch * CK;
        const unsigned short* p0 = va0 + cur * 8192;
        const unsigned short* p1 = va1 + cur * 8192;

        f32x4 acc[4][4];
#pragma unroll
        for (int j = 0; j < 4; ++j) {
            const float ev = -0.5f * e2l[c0 + 16 * j + l15];
            const f32x4 iv = {ev, ev, ev, ev};
#pragma unroll
            for (int i = 0; i < 4; ++i) acc[i][j] = iv;
        }

#pragma unroll
        for (int j = 0; j < 4; ++j) {
            short8 bh0 = *(const short8*)(p0 + j * 1024);
            short8 bh1 = *(const short8*)(p1 + j * 1024);
            short8 bl0 = *(const short8*)(p0 + j * 1024 + 4096);
            short8 bl1 = *(const short8*)(p1 + j * 1024 + 4096);
#pragma unroll
            for (int i = 0; i < 4; ++i) {
                f32x4 a = acc[i][j];
                a = __builtin_amdgcn_mfma_f32_16x16x32_bf16(ah[i][0], bh0, a, 0, 0, 0);
                a = __builtin_amdgcn_mfma_f32_16x16x32_bf16(ah[i][1], bh1, a, 0, 0, 0);
                a = __builtin_amdgcn_mfma_f32_16x16x32_bf16(ah[i][0], bl0, a, 0, 0, 0);
                a = __builtin_amdgcn_mfma_f32_16x16x32_bf16(ah[i][1], bl1, a, 0, 0, 0);
                a = __builtin_amdgcn_mfma_f32_16x16x32_bf16(al[i][0], bh0, a, 0, 0, 0);
                a = __builtin_amdgcn_mfma_f32_16x16x32_bf16(al[i][1], bh1, a, 0, 0, 0);
                acc[i][j] = a;
            }
        }

        // epilogue: C/D layout col=l15, row=quad*4+r (per 16-tile i); argmax d
#pragma unroll
        for (int j = 0; j < 4; ++j) {
            const int c = c0 + 16 * j + l15;
#pragma unroll
            for (int i = 0; i < 4; ++i)
#pragma unroll
                for (int r = 0; r < 4; ++r) {
                    float d = acc[i][j][r];
                    const int st = i * 4 + r;
                    bool gt = d > s1[st];
                    // running second-max: med3(d, s1_old, s2_old)
                    float ns2;
                    asm("v_med3_f32 %0, %1, %2, %3"
                        : "=v"(ns2) : "v"(d), "v"(s1[st]), "v"(s2[st]));
                    s2[st] = ns2;
                    c1[st] = gt ? c : c1[st];
                    s1[st] = fmaxf(s1[st], d);
                }
        }

        __syncthreads();   // next-chunk DMA landed; all waves done reading cur
        cur ^= 1;
    }

    // butterfly top-2 merge across the 16 lanes (same quad) sharing each row
#pragma unroll
    for (int st = 0; st < 16; ++st) {
#pragma unroll
        for (int m = 1; m < 16; m <<= 1) {
            float os1 = __shfl_xor(s1[st], m, 64);
            float os2 = __shfl_xor(s2[st], m, 64);
            int   oc1 = __shfl_xor(c1[st], m, 64);
            bool take = (os1 > s1[st]) || (os1 == s1[st] && oc1 < c1[st]);
            float loser = take ? s1[st] : os1;
            s2[st] = fmaxf(fmaxf(s2[st], os2), loser);
            if (take) { s1[st] = os1; c1[st] = oc1; }
        }
    }
    if (l15 == 0) {
#pragma unroll
        for (int st = 0; st < 16; ++st) {
            const int i = st >> 2, r = st & 3;
            const int row = r0w + 16 * i + 4 * quad + r;
            ind_ws[row] = c1[st];
            ind_out[row] = (float)c1[st];
            if (s1[st] - s2[st] < HEPS) {    // score gap = 2*(s1-s2) < EPS
                int p = atomicAdd(cnt, 1);
                list[p] = row;
            }
        }
    }
#undef STAGE
}

// ---- exact fp32 re-solve for flagged rows, batched 8 rows per pass ----
// Embed is streamed once per 8 rows (L2 traffic / 8 vs per-row scan).
__global__ void refine_kernel(const float* __restrict__ x,
                              const float* __restrict__ embed,
                              const float* __restrict__ e2g,
                              const int* __restrict__ cnt,
                              const int* __restrict__ list,
                              int* __restrict__ ind_ws,
                              float* __restrict__ ind_out) {
    __shared__ float xr[RB][DIM];                    // 2 KB
    __shared__ unsigned long long pw[4][RB];
    const int tid  = threadIdx.x;
    const int lane = tid & 63;
    const int wv   = tid >> 6;
    const int n = *cnt;
    for (int f0 = blockIdx.x * RB; f0 < n; f0 += gridDim.x * RB) {
        const int rc = min(RB, n - f0);
        __syncthreads();
        if (tid < RB * 16) {
            const int rr = tid >> 4, qq = tid & 15;
            const int row = list[f0 + (rr < rc ? rr : 0)];
            ((float4*)xr[rr])[qq] = ((const float4*)(x + (size_t)row * DIM))[qq];
        }
        __syncthreads();
        unsigned long long best[RB];
#pragma unroll
        for (int rr = 0; rr < RB; ++rr) best[rr] = ~0ull;
        for (int c = tid; c < K_CODES; c += 256) {
            const float4* ep = (const float4*)(embed + (size_t)c * DIM);
            float acc[RB];
#pragma unroll
            for (int rr = 0; rr < RB; ++rr) acc[rr] = 0.f;
#pragma unroll
            for (int q = 0; q < 16; ++q) {
                float4 ev = ep[q];
#pragma unroll
                for (int rr = 0; rr < RB; ++rr) {
                    float4 xv = ((const float4*)xr[rr])[q];   // broadcast read
                    acc[rr] = fmaf(xv.x, ev.x, acc[rr]);
                    acc[rr] = fmaf(xv.y, ev.y, acc[rr]);
                    acc[rr] = fmaf(xv.z, ev.z, acc[rr]);
                    acc[rr] = fmaf(xv.w, ev.w, acc[rr]);
                }
            }
            const float e2c = e2g[c];
#pragma unroll
            for (int rr = 0; rr < RB; ++rr) {
                float sc = fmaf(-2.f, acc[rr], e2c);
                unsigned long long key =
                    ((unsigned long long)fkey(sc) << 32) | (unsigned int)c;
                best[rr] = key < best[rr] ? key : best[rr];
            }
        }
#pragma unroll
        for (int rr = 0; rr < RB; ++rr)
#pragma unroll
            for (int m = 32; m > 0; m >>= 1) {
                unsigned long long o = __shfl_xor(best[rr], m, 64);
                best[rr] = o < best[rr] ? o : best[rr];
            }
        if (lane == 0)
#pragma unroll
            for (int rr = 0; rr < RB; ++rr) pw[wv][rr] = best[rr];
        __syncthreads();
        if (tid < rc) {
            unsigned long long b = pw[0][tid];
            b = pw[1][tid] < b ? pw[1][tid] : b;
            b = pw[2][tid] < b ? pw[2][tid] : b;
            b = pw[3][tid] < b ? pw[3][tid] : b;
            const int k = (int)(b & 0xFFFFFFFFull);
            const int row = list[f0 + tid];
            ind_ws[row] = k;
            ind_out[row] = (float)k;
        }
    }
}

// ---- gather quantize + scatter stats (one wave = one row) ----
__global__ void scatter_kernel(const float* __restrict__ x,
                               const float* __restrict__ embed,
                               const int* __restrict__ ind,
                               float* __restrict__ quant,
                               float* __restrict__ cs,
                               float* __restrict__ esum) {
    const int t = blockIdx.x * blockDim.x + threadIdx.x;
    const int row = t >> 6;
    const int d = t & 63;
    const int k = ind[row];
    quant[t] = embed[(size_t)k * DIM + d];
    atomicAdd(&esum[(size_t)k * DIM + d], x[t]);
    if (d == 0) atomicAdd(&cs[k], 1.0f);
}

extern "C" void kernel_launch(void* const* d_in, const int* in_sizes, int n_in,
                              void* d_out, int out_size, void* d_ws, size_t ws_size,
                              hipStream_t stream) {
    const float* x     = (const float*)d_in[0];
    const float* embed = (const float*)d_in[1];

    float* out     = (float*)d_out;
    float* quant   = out;                            // [N, D]
    float* ind_out = out + (size_t)N_ROWS * DIM;     // [N] (as float)
    float* cs      = ind_out + N_ROWS;               // [K]
    float* esum    = cs + K_CODES;                   // [K, D]

    // ws: e2 [K] | cnt [4 ints] | list [N] | ind_ws [N]   (~1.1 MB, unchanged)
    float* e2   = (float*)d_ws;
    int* cnt    = (int*)(e2 + K_CODES);
    int* list   = cnt + 4;
    int* ind_ws = list + N_ROWS;

    // bf16 hi/lo packed embed images live in the quant region of d_out (1 MB);
    // nothing reads them after dist, and scatter fully overwrites quant later.
    unsigned short* ebf = (unsigned short*)quant;

    hipMemsetAsync(cs, 0, (size_t)(K_CODES + K_CODES * DIM) * sizeof(float), stream);
    hipMemsetAsync(cnt, 0, sizeof(int), stream);

    e2_kernel<<<K_CODES / 256, 256, 0, stream>>>(embed, e2);
    pack_kernel<<<(NCH * 16384 / 16) / 256, 256, 0, stream>>>(embed, ebf);
    dist_argmin_kernel<<<N_ROWS / BROWS, 256, 0, stream>>>(
        x, ebf, e2, ind_ws, ind_out, cnt, list);
    refine_kernel<<<256, 256, 0, stream>>>(x, embed, e2, cnt, list, ind_ws, ind_out);
    scatter_kernel<<<(size_t)N_ROWS * DIM / 256, 256, 0, stream>>>(
        x, embed, ind_ws, quant, cs, esum);
}

// Round 2
// 1135.375 us; speedup vs baseline: 6.3960x; 6.3960x over previous
//
#include <hip/hip_runtime.h>

#define N_ROWS 131072
#define DIM 64
#define K_CODES 4096
#define BROWS 256            // rows per block = 4 waves x 64
#define CK 64                // cols per chunk
#define NCH (K_CODES / CK)   // 64 chunks
#define EPS 0.015625f        // flag margin in score space (>=15x bf16x3 error bound)
#define HEPS 0.0078125f      // EPS/2 in d-space (score = -2*d)
#define RB 4                 // refine rows per pass (8 spilled at any sane VGPR cap)

typedef __attribute__((ext_vector_type(8))) short short8;
typedef __attribute__((ext_vector_type(4))) float f32x4;

__device__ inline unsigned short bf16rn(float f) {      // round-nearest-even
    unsigned int u = __float_as_uint(f);
    u += 0x7FFFu + ((u >> 16) & 1u);
    return (unsigned short)(u >> 16);
}
// order-preserving float -> uint32 (finite scores)
__device__ inline unsigned int fkey(float f) {
    unsigned int u = __float_as_uint(f);
    return (u & 0x80000000u) ? ~u : (u | 0x80000000u);
}

__device__ __forceinline__ void gll16(const void* g, void* l) {
    __builtin_amdgcn_global_load_lds(
        (const __attribute__((address_space(1))) void*)g,
        (__attribute__((address_space(3))) void*)l, 16, 0, 0);
}

// ---- e2[k] = sum_d embed[k][d]^2 (exact fp32) ----
__global__ void e2_kernel(const float* __restrict__ embed, float* __restrict__ e2) {
    int k = blockIdx.x * blockDim.x + threadIdx.x;
    const float4* e = reinterpret_cast<const float4*>(embed + (size_t)k * DIM);
    float s = 0.f;
#pragma unroll
    for (int i = 0; i < DIM / 4; ++i) {
        float4 v = e[i];
        s = fmaf(v.x, v.x, s);
        s = fmaf(v.y, v.y, s);
        s = fmaf(v.z, v.z, s);
        s = fmaf(v.w, v.w, s);
    }
    e2[k] = s;
}

// ---- pack embed -> bf16 hi/lo "LDS images", one 16KB image per chunk ----
// Image layout per chunk: bytes [0,8192) = hi half, [8192,16384) = lo half.
// Within each half, phys byte p holds logical byte L = p ^ (((p>>7)&7)<<4)
// of a row-major [64 codes][64 bf16] tile (XOR swizzle keeps ds_read_b128
// bank-even; 16B granules map to 16B granules so linear global_load_lds works).
__global__ void pack_kernel(const float* __restrict__ embed,
                            unsigned short* __restrict__ ebf) {
    const int g = blockIdx.x * blockDim.x + threadIdx.x;   // granule id (16B each)
    const int ch  = g >> 10;                               // 1024 granules / chunk
    const int off = (g & 1023) << 4;                       // byte in 16KB image
    const int lohalf = off >> 13;                          // 0 = hi, 1 = lo
    const int p = off & 8191;
    const int L = p ^ (((p >> 7) & 7) << 4);
    const int row = L >> 7;
    const int d0  = (L & 127) >> 1;
    const float* ep = embed + ((size_t)(ch * 64 + row) * DIM + d0);
    float4 f0 = *(const float4*)ep;
    float4 f1 = *(const float4*)(ep + 4);
    float w[8] = {f0.x, f0.y, f0.z, f0.w, f1.x, f1.y, f1.z, f1.w};
    unsigned short o[8];
#pragma unroll
    for (int j = 0; j < 8; ++j) {
        unsigned short hb = bf16rn(w[j]);
        if (lohalf == 0) {
            o[j] = hb;
        } else {
            float hf = __uint_as_float(((unsigned int)hb) << 16);
            o[j] = bf16rn(w[j] - hf);
        }
    }
    *(uint4*)(ebf + (size_t)g * 8) = *(uint4*)o;
}

// ---- MFMA distance + fused top-2 argmax(dot - e2/2) ----
// Wave = 64 rows; A (xh,xl frags) in registers for the whole sweep.
// B tiles DMA'd via global_load_lds (double-buffered, prefetch-early/drain-late).
// acc init = -e2/2, then acc += xh*eh + xh*el + xl*eh (bf16x3); score = -2*acc.
__global__ __launch_bounds__(256, 2) void dist_argmin_kernel(
        const float* __restrict__ x, const unsigned short* __restrict__ ebf,
        const float* __restrict__ e2g, int* __restrict__ ind_ws,
        float* __restrict__ ind_out, int* __restrict__ cnt,
        int* __restrict__ list) {
    __shared__ unsigned short ebuf[2][8192];   // 2 x 16KB chunk images
    __shared__ float e2l[K_CODES];             // 16KB

    const int tid  = threadIdx.x;
    const int l15  = tid & 15;
    const int quad = (tid >> 4) & 3;
    const int wave = tid >> 6;
    const int r0w  = blockIdx.x * BROWS + wave * 64;

    const int lane16 = (tid & 63) << 4;
    const int uoff   = wave << 10;
    const char* ebfB = (const char*)ebf;
    char* lds0 = (char*)&ebuf[0][0];

#define STAGE(CH, BUF) do {                                              \
        const char* _g = ebfB + ((size_t)(CH) << 14) + uoff + lane16;    \
        char* _l = lds0 + ((BUF) << 14) + uoff;                          \
        gll16(_g,         _l);                                           \
        gll16(_g + 4096,  _l + 4096);                                    \
        gll16(_g + 8192,  _l + 8192);                                    \
        gll16(_g + 12288, _l + 12288);                                   \
    } while (0)

    // issue chunk-0 DMA first so it flies under the prologue work
    STAGE(0, 0);

    // e2 -> LDS (one-time)
    {
        const float4* s = (const float4*)e2g;
        float4* d = (float4*)e2l;
        for (int i = tid; i < K_CODES / 4; i += 256) d[i] = s[i];
    }

    // A-frags: A[m=l15][k=quad*8+j] per 16x16x32; rows 16i+l15, k-windows 32s+8q
    short8 ah[4][2], al[4][2];
#pragma unroll
    for (int i = 0; i < 4; ++i)
#pragma unroll
        for (int s = 0; s < 2; ++s) {
            const float* xp = x + (size_t)(r0w + 16 * i + l15) * DIM + 32 * s + 8 * quad;
            float4 f0 = *(const float4*)xp;
            float4 f1 = *(const float4*)(xp + 4);
            float w[8] = {f0.x, f0.y, f0.z, f0.w, f1.x, f1.y, f1.z, f1.w};
            short8 h, l;
#pragma unroll
            for (int j = 0; j < 8; ++j) {
                unsigned short hb = bf16rn(w[j]);
                float hf = __uint_as_float(((unsigned int)hb) << 16);
                h[j] = (short)hb;
                l[j] = (short)bf16rn(w[j] - hf);
            }
            ah[i][s] = h;
            al[i][s] = l;
        }

    // per-lane swizzled LDS frag bases (shorts): row=16j+l15, k-window w, granule
    // phys = j*2048B + l15*128B + (((w<<2)|quad) ^ (l15&7))<<4 ; lo half = +8192B
    const int fld = quad ^ (l15 & 7);
    const unsigned short* eb = &ebuf[0][0];
    const unsigned short* va0 = eb + ((l15 * 128 + (fld << 4)) >> 1);
    const unsigned short* va1 = eb + ((l15 * 128 + ((fld ^ 4) << 4)) >> 1);

    float s1[16], s2[16];
    int c1[16];
#pragma unroll
    for (int t = 0; t < 16; ++t) { s1[t] = -3.4e38f; s2[t] = -3.4e38f; c1[t] = 0; }

    __syncthreads();   // chunk 0 landed (drains vmcnt), e2l ready

    int cur = 0;
    for (int ch = 0; ch < NCH; ++ch) {
        STAGE((ch + 1) & (NCH - 1), cur ^ 1);   // prefetch next (wraps harmlessly)

        const int c0 = ch * CK;
        const unsigned short* p0 = va0 + cur * 8192;
        const unsigned short* p1 = va1 + cur * 8192;

        f32x4 acc[4][4];
#pragma unroll
        for (int j = 0; j < 4; ++j) {
            const float ev = -0.5f * e2l[c0 + 16 * j + l15];
            const f32x4 iv = {ev, ev, ev, ev};
#pragma unroll
            for (int i = 0; i < 4; ++i) acc[i][j] = iv;
        }

#pragma unroll
        for (int j = 0; j < 4; ++j) {
            short8 bh0 = *(const short8*)(p0 + j * 1024);
            short8 bh1 = *(const short8*)(p1 + j * 1024);
            short8 bl0 = *(const short8*)(p0 + j * 1024 + 4096);
            short8 bl1 = *(const short8*)(p1 + j * 1024 + 4096);
#pragma unroll
            for (int i = 0; i < 4; ++i) {
                f32x4 a = acc[i][j];
                a = __builtin_amdgcn_mfma_f32_16x16x32_bf16(ah[i][0], bh0, a, 0, 0, 0);
                a = __builtin_amdgcn_mfma_f32_16x16x32_bf16(ah[i][1], bh1, a, 0, 0, 0);
                a = __builtin_amdgcn_mfma_f32_16x16x32_bf16(ah[i][0], bl0, a, 0, 0, 0);
                a = __builtin_amdgcn_mfma_f32_16x16x32_bf16(ah[i][1], bl1, a, 0, 0, 0);
                a = __builtin_amdgcn_mfma_f32_16x16x32_bf16(al[i][0], bh0, a, 0, 0, 0);
                a = __builtin_amdgcn_mfma_f32_16x16x32_bf16(al[i][1], bh1, a, 0, 0, 0);
                acc[i][j] = a;
            }
        }

        // epilogue: C/D layout col=l15, row=quad*4+r (per 16-tile i); argmax d
#pragma unroll
        for (int j = 0; j < 4; ++j) {
            const int c = c0 + 16 * j + l15;
#pragma unroll
            for (int i = 0; i < 4; ++i)
#pragma unroll
                for (int r = 0; r < 4; ++r) {
                    float d = acc[i][j][r];
                    const int st = i * 4 + r;
                    bool gt = d > s1[st];
                    // running second-max: med3(d, s1_old, s2_old)
                    float ns2;
                    asm("v_med3_f32 %0, %1, %2, %3"
                        : "=v"(ns2) : "v"(d), "v"(s1[st]), "v"(s2[st]));
                    s2[st] = ns2;
                    c1[st] = gt ? c : c1[st];
                    s1[st] = fmaxf(s1[st], d);
                }
        }

        __syncthreads();   // next-chunk DMA landed; all waves done reading cur
        cur ^= 1;
    }

    // butterfly top-2 merge across the 16 lanes (same quad) sharing each row
#pragma unroll
    for (int st = 0; st < 16; ++st) {
#pragma unroll
        for (int m = 1; m < 16; m <<= 1) {
            float os1 = __shfl_xor(s1[st], m, 64);
            float os2 = __shfl_xor(s2[st], m, 64);
            int   oc1 = __shfl_xor(c1[st], m, 64);
            bool take = (os1 > s1[st]) || (os1 == s1[st] && oc1 < c1[st]);
            float loser = take ? s1[st] : os1;
            s2[st] = fmaxf(fmaxf(s2[st], os2), loser);
            if (take) { s1[st] = os1; c1[st] = oc1; }
        }
    }
    if (l15 == 0) {
#pragma unroll
        for (int st = 0; st < 16; ++st) {
            const int i = st >> 2, r = st & 3;
            const int row = r0w + 16 * i + 4 * quad + r;
            ind_ws[row] = c1[st];
            ind_out[row] = (float)c1[st];
            if (s1[st] - s2[st] < HEPS) {    // score gap = 2*(s1-s2) < EPS
                int p = atomicAdd(cnt, 1);
                list[p] = row;
            }
        }
    }
#undef STAGE
}

// ---- exact fp32 re-solve for flagged rows, batched RB rows per pass ----
// __launch_bounds__(256,2): cap VGPR at 256 so the RB-blocked loop NEVER spills
// (round 1's RB=8 + no bounds -> 64-VGPR cap -> scratch storm: 817MB writes).
__global__ __launch_bounds__(256, 2) void refine_kernel(
        const float* __restrict__ x,
        const float* __restrict__ embed,
        const float* __restrict__ e2g,
        const int* __restrict__ cnt,
        const int* __restrict__ list,
        int* __restrict__ ind_ws,
        float* __restrict__ ind_out) {
    __shared__ float xr[RB][DIM];                    // 1 KB
    __shared__ unsigned long long pw[4][RB];
    const int tid  = threadIdx.x;
    const int lane = tid & 63;
    const int wv   = tid >> 6;
    const int n = *cnt;
    for (int f0 = blockIdx.x * RB; f0 < n; f0 += gridDim.x * RB) {
        const int rc = min(RB, n - f0);
        __syncthreads();
        if (tid < RB * 16) {
            const int rr = tid >> 4, qq = tid & 15;
            const int row = list[f0 + (rr < rc ? rr : 0)];
            ((float4*)xr[rr])[qq] = ((const float4*)(x + (size_t)row * DIM))[qq];
        }
        __syncthreads();
        unsigned long long best[RB];
#pragma unroll
        for (int rr = 0; rr < RB; ++rr) best[rr] = ~0ull;
        for (int c = tid; c < K_CODES; c += 256) {
            const float4* ep = (const float4*)(embed + (size_t)c * DIM);
            float acc[RB];
#pragma unroll
            for (int rr = 0; rr < RB; ++rr) acc[rr] = 0.f;
#pragma unroll
            for (int q = 0; q < 16; ++q) {
                float4 ev = ep[q];
#pragma unroll
                for (int rr = 0; rr < RB; ++rr) {
                    float4 xv = ((const float4*)xr[rr])[q];   // broadcast read
                    acc[rr] = fmaf(xv.x, ev.x, acc[rr]);
                    acc[rr] = fmaf(xv.y, ev.y, acc[rr]);
                    acc[rr] = fmaf(xv.z, ev.z, acc[rr]);
                    acc[rr] = fmaf(xv.w, ev.w, acc[rr]);
                }
            }
            const float e2c = e2g[c];
#pragma unroll
            for (int rr = 0; rr < RB; ++rr) {
                float sc = fmaf(-2.f, acc[rr], e2c);
                unsigned long long key =
                    ((unsigned long long)fkey(sc) << 32) | (unsigned int)c;
                best[rr] = key < best[rr] ? key : best[rr];
            }
        }
#pragma unroll
        for (int rr = 0; rr < RB; ++rr)
#pragma unroll
            for (int m = 32; m > 0; m >>= 1) {
                unsigned long long o = __shfl_xor(best[rr], m, 64);
                best[rr] = o < best[rr] ? o : best[rr];
            }
        if (lane == 0)
#pragma unroll
            for (int rr = 0; rr < RB; ++rr) pw[wv][rr] = best[rr];
        __syncthreads();
        if (tid < rc) {
            unsigned long long b = pw[0][tid];
            b = pw[1][tid] < b ? pw[1][tid] : b;
            b = pw[2][tid] < b ? pw[2][tid] : b;
            b = pw[3][tid] < b ? pw[3][tid] : b;
            const int k = (int)(b & 0xFFFFFFFFull);
            const int row = list[f0 + tid];
            ind_ws[row] = k;
            ind_out[row] = (float)k;
        }
    }
}

// ---- gather quantize + scatter stats (one wave = one row) ----
__global__ void scatter_kernel(const float* __restrict__ x,
                               const float* __restrict__ embed,
                               const int* __restrict__ ind,
                               float* __restrict__ quant,
                               float* __restrict__ cs,
                               float* __restrict__ esum) {
    const int t = blockIdx.x * blockDim.x + threadIdx.x;
    const int row = t >> 6;
    const int d = t & 63;
    const int k = ind[row];
    quant[t] = embed[(size_t)k * DIM + d];
    atomicAdd(&esum[(size_t)k * DIM + d], x[t]);
    if (d == 0) atomicAdd(&cs[k], 1.0f);
}

extern "C" void kernel_launch(void* const* d_in, const int* in_sizes, int n_in,
                              void* d_out, int out_size, void* d_ws, size_t ws_size,
                              hipStream_t stream) {
    const float* x     = (const float*)d_in[0];
    const float* embed = (const float*)d_in[1];

    float* out     = (float*)d_out;
    float* quant   = out;                            // [N, D]
    float* ind_out = out + (size_t)N_ROWS * DIM;     // [N] (as float)
    float* cs      = ind_out + N_ROWS;               // [K]
    float* esum    = cs + K_CODES;                   // [K, D]

    // ws: e2 [K] | cnt [4 ints] | list [N] | ind_ws [N]   (~1.1 MB, unchanged)
    float* e2   = (float*)d_ws;
    int* cnt    = (int*)(e2 + K_CODES);
    int* list   = cnt + 4;
    int* ind_ws = list + N_ROWS;

    // bf16 hi/lo packed embed images live in the quant region of d_out (1 MB);
    // nothing reads them after dist, and scatter fully overwrites quant later.
    unsigned short* ebf = (unsigned short*)quant;

    hipMemsetAsync(cs, 0, (size_t)(K_CODES + K_CODES * DIM) * sizeof(float), stream);
    hipMemsetAsync(cnt, 0, sizeof(int), stream);

    e2_kernel<<<K_CODES / 256, 256, 0, stream>>>(embed, e2);
    pack_kernel<<<(NCH * 16384 / 16) / 256, 256, 0, stream>>>(embed, ebf);
    dist_argmin_kernel<<<N_ROWS / BROWS, 256, 0, stream>>>(
        x, ebf, e2, ind_ws, ind_out, cnt, list);
    refine_kernel<<<512, 256, 0, stream>>>(x, embed, e2, cnt, list, ind_ws, ind_out);
    scatter_kernel<<<(size_t)N_ROWS * DIM / 256, 256, 0, stream>>>(
        x, embed, ind_ws, quant, cs, esum);
}